// Round 4
// baseline (79761.914 us; speedup 1.0000x reference)
//
#include <hip/hip_runtime.h>
#include <hip/hip_bf16.h>
#include <hip/hip_cooperative_groups.h>

namespace cg = cooperative_groups;

#define BB 512
#define TT 512
#define DD 76
#define HH 256
#define G4 1024
#define NC 25
#define GRID_BLOCKS 256
#define NTHREADS 512

__device__ __forceinline__ float sigm(float v) { return 1.0f / (1.0f + __expf(-v)); }
__device__ __forceinline__ float tanh_f(float v) {
  float e = __expf(2.0f * v);
  return 1.0f - 2.0f / (e + 1.0f);   // e in [0, inf] -> result in [-1, 1], no NaN
}

// ---------------- weight repack: fp32 [k][4H] -> fp32 [k][j][4 gates] ----------------
__global__ void repack_kernel(const float* __restrict__ Wi1, const float* __restrict__ Wh1,
                              const float* __restrict__ Wi2, const float* __restrict__ Wh2,
                              float* __restrict__ W1f, float* __restrict__ W2f) {
  int idx = blockIdx.x * blockDim.x + threadIdx.x;
  const int N1 = (DD + HH) * G4;   // 332*1024
  const int N2 = (2 * HH) * G4;    // 512*1024
  if (idx < N1) {
    int k = idx >> 10, r = idx & 1023;
    int j = r >> 2, g = r & 3;
    int src = g * HH + j;
    W1f[idx] = (k < DD) ? Wi1[k * G4 + src] : Wh1[(k - DD) * G4 + src];
  } else if (idx < N1 + N2) {
    int d = idx - N1;
    int k = d >> 10, r = d & 1023;
    int j = r >> 2, g = r & 3;
    int src = g * HH + j;
    W2f[d] = (k < HH) ? Wi2[k * G4 + src] : Wh2[(k - HH) * G4 + src];
  }
}

// ---------------- persistent fused 2-layer LSTM (cooperative) ----------------
__global__ __launch_bounds__(NTHREADS) void lstm_kernel(
    const float* __restrict__ x,
    const float* __restrict__ b1, const float* __restrict__ b2,
    const float* __restrict__ Wd, const float* __restrict__ bd,
    const float* __restrict__ W1f, const float* __restrict__ W2f,
    float* __restrict__ h1buf, float* __restrict__ h2buf,
    float* __restrict__ out)
{
  cg::grid_group grid = cg::this_grid();

  __shared__ float lds_x[32][80];    // x_t tile (32 rows x 76), padded
  __shared__ float lds_h[32][260];   // h tile (32 rows x 256), stride 260 (1040B, 16B mult)

  const int tid = threadIdx.x;
  const int jl = tid & 15, bl = tid >> 4;          // 16 j-lanes x 32 b-lanes
  const int bt = blockIdx.x >> 4, jt = blockIdx.x & 15;
  const int j = jt * 16 + jl;                      // hidden unit this thread owns
  const int row = bt * 32 + bl;                    // batch row this thread owns

  float bias1[4], bias2[4];
#pragma unroll
  for (int g = 0; g < 4; ++g) {
    bias1[g] = b1[g * HH + j];
    bias2[g] = b2[g * HH + j];
  }
  float c1 = 0.f, c2 = 0.f;

  const float4* W1 = (const float4*)W1f;  // [332*256] gate-quads
  const float4* W2 = (const float4*)W2f;  // [512*256]

  for (int t = 0; t < TT; ++t) {
    const int pb = t & 1, cb = pb ^ 1;
    float* __restrict__ h1p = h1buf + pb * (BB * HH);
    float* __restrict__ h1c = h1buf + cb * (BB * HH);
    float* __restrict__ h2p = h2buf + pb * (BB * HH);
    float* __restrict__ h2c = h2buf + cb * (BB * HH);

    // ---------- Phase A: layer-1 step t ----------
    for (int idx = tid; idx < 32 * DD; idx += NTHREADS) {
      int r = idx / DD, d = idx - r * DD;
      lds_x[r][d] = x[((size_t)(bt * 32 + r) * TT + t) * DD + d];
    }
    if (t > 0) {
      const float4* src = (const float4*)(h1p + bt * 32 * HH);
      for (int idx = tid; idx < (32 * HH) / 4; idx += NTHREADS) {
        int r = idx >> 6, c = idx & 63;
        float4 v = src[idx];
        *(float4*)&lds_h[r][c * 4] = v;
      }
    }
    __syncthreads();

    float a0 = bias1[0], a1 = bias1[1], a2 = bias1[2], a3 = bias1[3];
#pragma unroll 4
    for (int k = 0; k < DD; ++k) {
      float a = lds_x[bl][k];
      float4 w = W1[k * HH + j];
      a0 += a * w.x; a1 += a * w.y; a2 += a * w.z; a3 += a * w.w;
    }
    if (t > 0) {
#pragma unroll 4
      for (int k = 0; k < HH; ++k) {
        float a = lds_h[bl][k];
        float4 w = W1[(DD + k) * HH + j];
        a0 += a * w.x; a1 += a * w.y; a2 += a * w.z; a3 += a * w.w;
      }
    }
    {
      float ig = sigm(a0), fg = sigm(a1), gg = tanh_f(a2), og = sigm(a3);
      c1 = fg * c1 + ig * gg;
      h1c[row * HH + j] = og * tanh_f(c1);
    }
    grid.sync();

    // ---------- Phase B: layer-2 step t ----------
    {
      const float4* src = (const float4*)(h1c + bt * 32 * HH);
      for (int idx = tid; idx < (32 * HH) / 4; idx += NTHREADS) {
        int r = idx >> 6, c = idx & 63;
        float4 v = src[idx];
        *(float4*)&lds_h[r][c * 4] = v;
      }
    }
    __syncthreads();
    float z0 = bias2[0], z1 = bias2[1], z2 = bias2[2], z3 = bias2[3];
#pragma unroll 4
    for (int k = 0; k < HH; ++k) {
      float a = lds_h[bl][k];
      float4 w = W2[k * HH + j];
      z0 += a * w.x; z1 += a * w.y; z2 += a * w.z; z3 += a * w.w;
    }
    __syncthreads();
    if (t > 0) {
      const float4* src = (const float4*)(h2p + bt * 32 * HH);
      for (int idx = tid; idx < (32 * HH) / 4; idx += NTHREADS) {
        int r = idx >> 6, c = idx & 63;
        float4 v = src[idx];
        *(float4*)&lds_h[r][c * 4] = v;
      }
      __syncthreads();
#pragma unroll 4
      for (int k = 0; k < HH; ++k) {
        float a = lds_h[bl][k];
        float4 w = W2[(HH + k) * HH + j];
        z0 += a * w.x; z1 += a * w.y; z2 += a * w.z; z3 += a * w.w;
      }
    }
    {
      float ig = sigm(z0), fg = sigm(z1), gg = tanh_f(z2), og = sigm(z3);
      c2 = fg * c2 + ig * gg;
      h2c[row * HH + j] = og * tanh_f(c2);
    }
    grid.sync();
  }

  // ---------- dense head: logits = h2[:, T-1] @ Wd + bd ----------
  // t=511: pb=1, cb=0 -> feats are h2buf[0 .. B*H)
  const float* feats = h2buf;
  if (tid < 2 * NC) {
    int r = blockIdx.x * 2 + (tid / NC);
    int n = tid % NC;
    float s = bd[n];
    const float* f = feats + r * HH;
#pragma unroll 8
    for (int k = 0; k < HH; ++k) s += f[k] * Wd[k * NC + n];
    out[r * NC + n] = s;
  }
}

extern "C" void kernel_launch(void* const* d_in, const int* in_sizes, int n_in,
                              void* d_out, int out_size, void* d_ws, size_t ws_size,
                              hipStream_t stream) {
  const float* x   = (const float*)d_in[0];
  const float* Wi1 = (const float*)d_in[1];
  const float* Wh1 = (const float*)d_in[2];
  const float* b1  = (const float*)d_in[3];
  const float* Wi2 = (const float*)d_in[4];
  const float* Wh2 = (const float*)d_in[5];
  const float* b2  = (const float*)d_in[6];
  const float* Wd  = (const float*)d_in[7];
  const float* bd  = (const float*)d_in[8];

  char* ws = (char*)d_ws;
  // ws layout (bytes):
  //   [0, 1MB)            h1 ping-pong fp32 [2][512][256]
  //   [1MB, 2MB)          h2 ping-pong fp32 [2][512][256]
  //   [2MB, +1.30MB)      W1f fp32 332*1024 gate-interleaved
  //   [.., +2MB)          W2f fp32 512*1024 gate-interleaved    total ~5.4 MB
  float* h1  = (float*)(ws);
  float* h2  = (float*)(ws + (1u << 20));
  float* W1f = (float*)(ws + (2u << 20));
  float* W2f = (float*)(ws + (2u << 20) + 1359872u);
  float* out = (float*)d_out;

  const int total = (DD + HH) * G4 + (2 * HH) * G4;  // 864256
  repack_kernel<<<(total + 255) / 256, 256, 0, stream>>>(Wi1, Wh1, Wi2, Wh2, W1f, W2f);

  void* args[] = {
    (void*)&x, (void*)&b1, (void*)&b2, (void*)&Wd, (void*)&bd,
    (void*)&W1f, (void*)&W2f, (void*)&h1, (void*)&h2, (void*)&out
  };
  // Cooperative launch (harness-supported). If it fails, leave d_out zeroed:
  // a finite absmax (~0.334) then cleanly signals "coop launch rejected"
  // as opposed to a math/addressing bug.
  (void)hipLaunchCooperativeKernel((void*)lstm_kernel, dim3(GRID_BLOCKS),
                                   dim3(NTHREADS), args, 0, stream);
}

// Round 5
// 47803.473 us; speedup vs baseline: 1.6685x; 1.6685x over previous
//
#include <hip/hip_runtime.h>
#include <hip/hip_cooperative_groups.h>

namespace cg = cooperative_groups;

#define BB 512
#define TT 512
#define DD 76
#define HH 256
#define G4 1024
#define NC 25
#define GRID_BLOCKS 256
#define NTHREADS 512
#define JT 8            // hidden columns per block (32 j-tiles)
#define RT 64           // batch rows per block (8 row-tiles)
#define APAD 132        // act row stride in fp32 (bank-spread + 16B aligned)
#define KW (DD + HH + 2 * HH)   // 844 weight k-rows (L1: 76+256, L2: 256+256)

__device__ __forceinline__ float sigm(float v) { return 1.0f / (1.0f + __expf(-v)); }
__device__ __forceinline__ float tanh_f(float v) {
  float e = __expf(2.0f * v);
  return 1.0f - 2.0f / (e + 1.0f);   // e in [0, inf] -> [-1, 1], no NaN
}

// ---------------- weight repack: fp32 [k][4H] -> fp32 [k][j][4 gates] ----------------
__global__ void repack_kernel(const float* __restrict__ Wi1, const float* __restrict__ Wh1,
                              const float* __restrict__ Wi2, const float* __restrict__ Wh2,
                              float* __restrict__ W1f, float* __restrict__ W2f) {
  int idx = blockIdx.x * blockDim.x + threadIdx.x;
  const int N1 = (DD + HH) * G4;   // 332*1024
  const int N2 = (2 * HH) * G4;    // 512*1024
  if (idx < N1) {
    int k = idx >> 10, r = idx & 1023;
    int j = r >> 2, g = r & 3;
    int src = g * HH + j;
    W1f[idx] = (k < DD) ? Wi1[k * G4 + src] : Wh1[(k - DD) * G4 + src];
  } else if (idx < N1 + N2) {
    int d = idx - N1;
    int k = d >> 10, r = d & 1023;
    int j = r >> 2, g = r & 3;
    int src = g * HH + j;
    W2f[d] = (k < HH) ? Wi2[k * G4 + src] : Wh2[(k - HH) * G4 + src];
  }
}

// accumulate 4 gate dot-products over a k-chunk from LDS
__device__ __forceinline__ void acc4(const float* __restrict__ wlds,
                                     const float* __restrict__ arow, int jl,
                                     int wofs, int klen,
                                     float& A0, float& A1, float& A2, float& A3) {
  const float4* wq = (const float4*)wlds;   // [KW*8] gate-quads; thread's at [k*8 + jl]
#pragma unroll 4
  for (int kk = 0; kk < klen; kk += 4) {
    float4 av = *(const float4*)(arow + kk);
    float4 w0 = wq[(wofs + kk + 0) * 8 + jl];
    float4 w1 = wq[(wofs + kk + 1) * 8 + jl];
    float4 w2 = wq[(wofs + kk + 2) * 8 + jl];
    float4 w3 = wq[(wofs + kk + 3) * 8 + jl];
    A0 += av.x * w0.x; A1 += av.x * w0.y; A2 += av.x * w0.z; A3 += av.x * w0.w;
    A0 += av.y * w1.x; A1 += av.y * w1.y; A2 += av.y * w1.z; A3 += av.y * w1.w;
    A0 += av.z * w2.x; A1 += av.z * w2.y; A2 += av.z * w2.z; A3 += av.z * w2.w;
    A0 += av.w * w3.x; A1 += av.w * w3.y; A2 += av.w * w3.z; A3 += av.w * w3.w;
  }
}

// ---------------- persistent fused 2-layer LSTM (cooperative) ----------------
__global__ __launch_bounds__(NTHREADS) void lstm_kernel(
    const float* __restrict__ x,
    const float* __restrict__ b1, const float* __restrict__ b2,
    const float* __restrict__ Wd, const float* __restrict__ bd,
    const float* __restrict__ W1f, const float* __restrict__ W2f,
    float* __restrict__ h1buf, float* __restrict__ h2buf,
    float* __restrict__ out)
{
  cg::grid_group grid = cg::this_grid();

  __shared__ float wlds[KW * 32];     // 108,032 B: [844][8 j][4 gates]
  __shared__ float act[RT * APAD];    //  33,792 B: [64 rows][132]

  const int tid = threadIdx.x;
  const int jl = tid & 7, rl = tid >> 3;     // 8 j-lanes x 64 rows
  const int jt = blockIdx.x & 31, bt = blockIdx.x >> 5;
  const int j = jt * JT + jl;                // hidden unit this thread owns
  const int row = bt * RT + rl;              // batch row this thread owns

  // ---- stage this block's weight slice into LDS (once; reused all 512 steps) ----
  {
    const float4* W1q = (const float4*)W1f;  // float4 idx: k*256 + j
    const float4* W2q = (const float4*)W2f;
    float4* wq = (float4*)wlds;
    for (int i = tid; i < (DD + HH) * 8; i += NTHREADS) {
      int k = i >> 3, q = i & 7;
      wq[k * 8 + q] = W1q[k * 256 + jt * 8 + q];
    }
    for (int i = tid; i < (2 * HH) * 8; i += NTHREADS) {
      int k = i >> 3, q = i & 7;
      wq[(DD + HH + k) * 8 + q] = W2q[k * 256 + jt * 8 + q];
    }
  }
  float bias1[4], bias2[4];
#pragma unroll
  for (int g = 0; g < 4; ++g) {
    bias1[g] = b1[g * HH + j];
    bias2[g] = b2[g * HH + j];
  }
  float c1 = 0.f, c2 = 0.f;
  const float* arow = act + rl * APAD;
  __syncthreads();

  for (int t = 0; t < TT; ++t) {
    const int pb = t & 1, cb = pb ^ 1;
    float* __restrict__ h1p = h1buf + pb * (BB * HH);
    float* __restrict__ h1c = h1buf + cb * (BB * HH);
    float* __restrict__ h2p = h2buf + pb * (BB * HH);
    float* __restrict__ h2c = h2buf + cb * (BB * HH);

    // ---------- Phase A: layer-1 step t ----------
    float a0 = bias1[0], a1 = bias1[1], a2 = bias1[2], a3 = bias1[3];

    // chunk X: stage x-tile [64 rows x 76]
    for (int e = tid; e < RT * DD; e += NTHREADS) {
      int r = e / DD, d = e - r * DD;
      act[r * APAD + d] = x[((size_t)(bt * RT + r) * TT + t) * DD + d];
    }
    __syncthreads();
    acc4(wlds, arow, jl, 0, DD, a0, a1, a2, a3);

    if (t > 0) {
      // h1[t-1] in two 128-k halves
#pragma unroll
      for (int half = 0; half < 2; ++half) {
        __syncthreads();
        const int k0 = half * 128;
        const float4* src = (const float4*)h1p;
        for (int q = tid; q < RT * 32; q += NTHREADS) {
          int r = q >> 5, qq = q & 31;
          float4 v = src[(bt * RT + r) * (HH / 4) + (k0 >> 2) + qq];
          *(float4*)(act + r * APAD + qq * 4) = v;
        }
        __syncthreads();
        acc4(wlds, arow, jl, DD + k0, 128, a0, a1, a2, a3);
      }
    }
    {
      float ig = sigm(a0), fg = sigm(a1), gg = tanh_f(a2), og = sigm(a3);
      c1 = fg * c1 + ig * gg;
      h1c[row * HH + j] = og * tanh_f(c1);
    }
    grid.sync();

    // ---------- Phase B: layer-2 step t ----------
    float z0 = bias2[0], z1 = bias2[1], z2 = bias2[2], z3 = bias2[3];

    // h1[t] (just produced) in two halves; weights at wofs 332 / 460
#pragma unroll
    for (int half = 0; half < 2; ++half) {
      __syncthreads();
      const int k0 = half * 128;
      const float4* src = (const float4*)h1c;
      for (int q = tid; q < RT * 32; q += NTHREADS) {
        int r = q >> 5, qq = q & 31;
        float4 v = src[(bt * RT + r) * (HH / 4) + (k0 >> 2) + qq];
        *(float4*)(act + r * APAD + qq * 4) = v;
      }
      __syncthreads();
      acc4(wlds, arow, jl, (DD + HH) + k0, 128, z0, z1, z2, z3);
    }
    if (t > 0) {
      // h2[t-1] in two halves; weights at wofs 588 / 716
#pragma unroll
      for (int half = 0; half < 2; ++half) {
        __syncthreads();
        const int k0 = half * 128;
        const float4* src = (const float4*)h2p;
        for (int q = tid; q < RT * 32; q += NTHREADS) {
          int r = q >> 5, qq = q & 31;
          float4 v = src[(bt * RT + r) * (HH / 4) + (k0 >> 2) + qq];
          *(float4*)(act + r * APAD + qq * 4) = v;
        }
        __syncthreads();
        acc4(wlds, arow, jl, (DD + HH) + HH + k0, 128, z0, z1, z2, z3);
      }
    }
    {
      float ig = sigm(z0), fg = sigm(z1), gg = tanh_f(z2), og = sigm(z3);
      c2 = fg * c2 + ig * gg;
      h2c[row * HH + j] = og * tanh_f(c2);
    }
    grid.sync();
  }

  // ---------- dense head: logits = h2[:, T-1] @ Wd + bd ----------
  // t=511: pb=1, cb=0 -> feats are h2buf[0 .. B*H)
  const float* feats = h2buf;
  if (tid < 2 * NC) {
    int r = blockIdx.x * 2 + (tid / NC);
    int n = tid % NC;
    float s = bd[n];
    const float* f = feats + r * HH;
#pragma unroll 8
    for (int k = 0; k < HH; ++k) s += f[k] * Wd[k * NC + n];
    out[r * NC + n] = s;
  }
}

extern "C" void kernel_launch(void* const* d_in, const int* in_sizes, int n_in,
                              void* d_out, int out_size, void* d_ws, size_t ws_size,
                              hipStream_t stream) {
  const float* x   = (const float*)d_in[0];
  const float* Wi1 = (const float*)d_in[1];
  const float* Wh1 = (const float*)d_in[2];
  const float* b1  = (const float*)d_in[3];
  const float* Wi2 = (const float*)d_in[4];
  const float* Wh2 = (const float*)d_in[5];
  const float* b2  = (const float*)d_in[6];
  const float* Wd  = (const float*)d_in[7];
  const float* bd  = (const float*)d_in[8];

  char* ws = (char*)d_ws;
  // ws layout (bytes):
  //   [0, 1MB)            h1 ping-pong fp32 [2][512][256]
  //   [1MB, 2MB)          h2 ping-pong fp32 [2][512][256]
  //   [2MB, +1.30MB)      W1f fp32 332*1024 gate-interleaved
  //   [.., +2MB)          W2f fp32 512*1024 gate-interleaved    total ~5.4 MB
  float* h1  = (float*)(ws);
  float* h2  = (float*)(ws + (1u << 20));
  float* W1f = (float*)(ws + (2u << 20));
  float* W2f = (float*)(ws + (2u << 20) + 1359872u);
  float* out = (float*)d_out;

  const int total = (DD + HH) * G4 + (2 * HH) * G4;  // 864256
  repack_kernel<<<(total + 255) / 256, 256, 0, stream>>>(Wi1, Wh1, Wi2, Wh2, W1f, W2f);

  void* args[] = {
    (void*)&x, (void*)&b1, (void*)&b2, (void*)&Wd, (void*)&bd,
    (void*)&W1f, (void*)&W2f, (void*)&h1, (void*)&h2, (void*)&out
  };
  (void)hipLaunchCooperativeKernel((void*)lstm_kernel, dim3(GRID_BLOCKS),
                                   dim3(NTHREADS), args, 0, stream);
}

// Round 6
// 27210.522 us; speedup vs baseline: 2.9313x; 1.7568x over previous
//
#include <hip/hip_runtime.h>
#include <hip/hip_cooperative_groups.h>

namespace cg = cooperative_groups;

#define BB 512
#define TT 512
#define DD 76
#define HH 256
#define NC 25
#define NBLK 256
#define NTHREADS 512
#define BBHH (BB * HH)

#define K1 352      // L1 virtual K: 76 x | 256 h | 20 zero-pad (multiple of 32)
#define K2 512      // L2 K: 256 h1 | 256 h2
#define WS1 360     // LDS k-stride (u16) for W1 planes
#define WS2 520     // LDS k-stride (u16) for W2 planes
#define ACT_S 136   // LDS act row stride (u16)
#define KC 128      // act chunk width

typedef unsigned short u16;
typedef unsigned int u32;
typedef __attribute__((ext_vector_type(8))) short bf16x8;
typedef __attribute__((ext_vector_type(4))) float f32x4;

__device__ __forceinline__ float bf2f(u16 v) {
  union { u32 u; float f; } c; c.u = ((u32)v) << 16; return c.f;
}
__device__ __forceinline__ u16 f2bf(float f) {
  union { u32 u; float f; } c; c.f = f;
  u32 r = c.u + 0x7FFFu + ((c.u >> 16) & 1u);   // RNE
  return (u16)(r >> 16);
}
__device__ __forceinline__ void split2(float f, u16& h, u16& l) {
  u16 hh = f2bf(f);
  float r = f - bf2f(hh);
  h = hh; l = f2bf(r);
}
__device__ __forceinline__ float sigm(float v) { return 1.0f / (1.0f + __expf(-v)); }
__device__ __forceinline__ float tanh_f(float v) {
  float e = __expf(2.0f * v);
  return 1.0f - 2.0f / (e + 1.0f);
}
__device__ __forceinline__ float pick4(int m, float a, float b, float c, float d) {
  return m == 0 ? a : (m == 1 ? b : (m == 2 ? c : d));
}

// ---- repack: fp32 [k][4H] -> hi/lo bf16 planes, layout [c=4j+g][k] with L1 zero-pad ----
__global__ void repack_kernel(const float* __restrict__ Wi1, const float* __restrict__ Wh1,
                              const float* __restrict__ Wi2, const float* __restrict__ Wh2,
                              u16* __restrict__ w1hg, u16* __restrict__ w1lg,
                              u16* __restrict__ w2hg, u16* __restrict__ w2lg) {
  int idx = blockIdx.x * blockDim.x + threadIdx.x;
  const int N1 = 1024 * K1;
  if (idx < N1) {
    int c = idx / K1, k = idx - c * K1;
    int src = (c & 3) * HH + (c >> 2);
    float v = 0.f;
    if (k < DD) v = Wi1[k * 1024 + src];
    else if (k < DD + HH) v = Wh1[(k - DD) * 1024 + src];
    u16 h, l; split2(v, h, l);
    w1hg[idx] = h; w1lg[idx] = l;
  } else if (idx < N1 + 1024 * K2) {
    int d = idx - N1;
    int c = d >> 9, k = d & 511;
    int src = (c & 3) * HH + (c >> 2);
    float v = (k < HH) ? Wi2[k * 1024 + src] : Wh2[(k - HH) * 1024 + src];
    u16 h, l; split2(v, h, l);
    w2hg[d] = h; w2lg[d] = l;
  }
}

// stage a 128-wide act chunk from an h-buffer (rows of HH floats), split hi/lo
#define STAGE_H128(srcbase, kofs)                                                  \
  for (int i = tid; i < 64 * 32; i += NTHREADS) {                                  \
    int r_ = i >> 5, c4_ = i & 31;                                                 \
    float4 v_ = *(const float4*)((srcbase) + (size_t)(row0 + r_) * HH + (kofs) + c4_ * 4); \
    u16 h0_, l0_, h1_, l1_, h2_, l2_, h3_, l3_;                                    \
    split2(v_.x, h0_, l0_); split2(v_.y, h1_, l1_);                                \
    split2(v_.z, h2_, l2_); split2(v_.w, h3_, l3_);                                \
    *(ushort4*)&ath[r_ * ACT_S + c4_ * 4] = make_ushort4(h0_, h1_, h2_, h3_);      \
    *(ushort4*)&atl[r_ * ACT_S + c4_ * 4] = make_ushort4(l0_, l1_, l2_, l3_);      \
  }

// stage an L1 act chunk: k<76 -> x[.,tt,.]; 76..331 -> h1src (or 0); else 0
#define STAGE_L1(chunk, tt, h1src, width)                                          \
  for (int i = tid; i < 64 * (width); i += NTHREADS) {                             \
    int r_ = i / (width), kk_ = i - r_ * (width);                                  \
    int kv_ = (chunk) * KC + kk_;                                                  \
    float v_ = 0.f;                                                                \
    if (kv_ < DD) v_ = x[((size_t)(row0 + r_) * TT + (tt)) * DD + kv_];            \
    else if (kv_ < DD + HH && (h1src) != nullptr)                                  \
      v_ = ((const float*)(h1src))[(size_t)(row0 + r_) * HH + kv_ - DD];           \
    u16 hh_, ll_; split2(v_, hh_, ll_);                                            \
    ath[r_ * ACT_S + kk_] = hh_; atl[r_ * ACT_S + kk_] = ll_;                      \
  }

// 3-term split-fp32 MFMA over one staged chunk
#define MFMA_CHUNK(Bh, Bl, wofs, nks)                                              \
  for (int s_ = 0; s_ < (nks); ++s_) {                                             \
    const int ko_ = s_ * 32 + qd * 8;                                              \
    bf16x8 a_h = *(const bf16x8*)(wA + ko_);                                       \
    bf16x8 a_l = *(const bf16x8*)(wAl + ko_);                                      \
    bf16x8 b_h = *(const bf16x8*)((Bh) + (wofs) + ko_);                            \
    bf16x8 b_l = *(const bf16x8*)((Bl) + (wofs) + ko_);                            \
    accA = __builtin_amdgcn_mfma_f32_16x16x32_bf16(a_h, b_h, accA, 0, 0, 0);       \
    accB = __builtin_amdgcn_mfma_f32_16x16x32_bf16(a_h, b_l, accB, 0, 0, 0);       \
    accC = __builtin_amdgcn_mfma_f32_16x16x32_bf16(a_l, b_h, accC, 0, 0, 0);       \
  }

__global__ __launch_bounds__(NTHREADS) void lstm_kernel(
    const float* __restrict__ x,
    const float* __restrict__ b1, const float* __restrict__ b2,
    const float* __restrict__ Wd, const float* __restrict__ bd,
    const u16* __restrict__ w1hg, const u16* __restrict__ w1lg,
    const u16* __restrict__ w2hg, const u16* __restrict__ w2lg,
    float* __restrict__ h1buf, float* __restrict__ h2buf,
    float* __restrict__ out)
{
  cg::grid_group grid = cg::this_grid();

  __shared__ u16 w1h[32 * WS1], w1l[32 * WS1];   // 46,080 B
  __shared__ u16 w2h[32 * WS2], w2l[32 * WS2];   // 66,560 B
  __shared__ u16 ath[64 * ACT_S], atl[64 * ACT_S]; // 34,816 B  (total 147,456)

  const int tid = threadIdx.x;
  const int lane = tid & 63;
  const int wv = tid >> 6;            // 0..7
  const int mf = wv & 3;              // M-frag: rows mf*16..
  const int nf = wv >> 2;             // 0..1: cols nf*16..
  const int nl = lane & 15;
  const int qd = lane >> 4;           // 0..3
  const int bt = blockIdx.x & 7;      // row-group (XCD-aligned: same-bt blocks share act reads)
  const int jt = blockIdx.x >> 3;     // 0..31 col-group
  const int row0 = bt * 64;

  // ---- stage weight slices to LDS once (u32 copies) ----
  for (int i = tid; i < 32 * (K1 / 2); i += NTHREADS) {      // 176 u32 per col
    int c = i / 176, kk = i - c * 176;
    ((u32*)&w1h[c * WS1])[kk] = ((const u32*)(w1hg + (size_t)(jt * 32 + c) * K1))[kk];
    ((u32*)&w1l[c * WS1])[kk] = ((const u32*)(w1lg + (size_t)(jt * 32 + c) * K1))[kk];
  }
  for (int i = tid; i < 32 * (K2 / 2); i += NTHREADS) {      // 256 u32 per col
    int c = i >> 8, kk = i & 255;
    ((u32*)&w2h[c * WS2])[kk] = ((const u32*)(w2hg + (size_t)(jt * 32 + c) * K2))[kk];
    ((u32*)&w2l[c * WS2])[kk] = ((const u32*)(w2lg + (size_t)(jt * 32 + c) * K2))[kk];
  }

  const int cg_col = jt * 32 + nf * 16 + nl;   // global gate-col 0..1023
  const int jg = cg_col >> 2;                  // hidden unit
  const int gi = cg_col & 3;                   // this lane's gate
  const float bias1 = b1[gi * HH + jg];
  const float bias2 = b2[gi * HH + jg];
  const int rbase = row0 + mf * 16 + qd * 4;   // first of this lane's 4 D rows
  float c1s[4] = {0.f, 0.f, 0.f, 0.f}, c2s[4] = {0.f, 0.f, 0.f, 0.f};

  const u16* wA  = ath + (mf * 16 + nl) * ACT_S;   // A-frag row base (hi)
  const u16* wAl = atl + (mf * 16 + nl) * ACT_S;   // (lo)
  const int cl = nf * 16 + nl;                     // local col 0..31
  const u16* wB1h = w1h + cl * WS1;
  const u16* wB1l = w1l + cl * WS1;
  const u16* wB2h = w2h + cl * WS2;
  const u16* wB2l = w2l + cl * WS2;

  // ---- prologue: h1[0] = L1(x[0], h1[-1]=0); only chunk 0 is non-zero ----
  {
    f32x4 accA = {bias1, bias1, bias1, bias1};
    f32x4 accB = {0.f, 0.f, 0.f, 0.f}, accC = {0.f, 0.f, 0.f, 0.f};
    __syncthreads();
    STAGE_L1(0, 0, (const float*)nullptr, KC);
    __syncthreads();
    MFMA_CHUNK(wB1h, wB1l, 0, 4);
    f32x4 z = accA + accB + accC;
#pragma unroll
    for (int r = 0; r < 4; ++r) {
      float zr = z[r];
      float s1 = __shfl_xor(zr, 1), s2 = __shfl_xor(zr, 2), s3 = __shfl_xor(zr, 3);
      float g0 = pick4(gi, zr, s1, s2, s3);
      float g1 = pick4(gi ^ 1, zr, s1, s2, s3);
      float g2 = pick4(gi ^ 2, zr, s1, s2, s3);
      float g3 = pick4(gi ^ 3, zr, s1, s2, s3);
      float ig = sigm(g0), fg = sigm(g1), gg = tanh_f(g2), og = sigm(g3);
      c1s[r] = fg * c1s[r] + ig * gg;
      float hv = og * tanh_f(c1s[r]);
      if (gi == 0) h1buf[(size_t)(rbase + r) * HH + jg] = hv;   // slot 0
    }
  }
  grid.sync();

  // ---- main loop: phase t computes L2[t] and L1[t+1]; one grid.sync per phase ----
#pragma unroll 1
  for (int t = 0; t < TT; ++t) {
    const float* h1cur = h1buf + (t & 1) * BBHH;
    float* h1nxt = h1buf + ((t + 1) & 1) * BBHH;
    const float* h2prv = h2buf + ((t + 1) & 1) * BBHH;   // == (t-1)&1
    float* h2cur = h2buf + (t & 1) * BBHH;

    // ----- L2[t]: z2 = h1[t] @ Wi2 + h2[t-1] @ Wh2 + b2 -----
    {
      f32x4 accA = {bias2, bias2, bias2, bias2};
      f32x4 accB = {0.f, 0.f, 0.f, 0.f}, accC = {0.f, 0.f, 0.f, 0.f};
      __syncthreads(); STAGE_H128(h1cur, 0);   __syncthreads(); MFMA_CHUNK(wB2h, wB2l, 0, 4);
      __syncthreads(); STAGE_H128(h1cur, 128); __syncthreads(); MFMA_CHUNK(wB2h, wB2l, 128, 4);
      if (t > 0) {
        __syncthreads(); STAGE_H128(h2prv, 0);   __syncthreads(); MFMA_CHUNK(wB2h, wB2l, 256, 4);
        __syncthreads(); STAGE_H128(h2prv, 128); __syncthreads(); MFMA_CHUNK(wB2h, wB2l, 384, 4);
      }
      f32x4 z = accA + accB + accC;
#pragma unroll
      for (int r = 0; r < 4; ++r) {
        float zr = z[r];
        float s1 = __shfl_xor(zr, 1), s2 = __shfl_xor(zr, 2), s3 = __shfl_xor(zr, 3);
        float g0 = pick4(gi, zr, s1, s2, s3);
        float g1 = pick4(gi ^ 1, zr, s1, s2, s3);
        float g2 = pick4(gi ^ 2, zr, s1, s2, s3);
        float g3 = pick4(gi ^ 3, zr, s1, s2, s3);
        float ig = sigm(g0), fg = sigm(g1), gg = tanh_f(g2), og = sigm(g3);
        c2s[r] = fg * c2s[r] + ig * gg;
        float hv = og * tanh_f(c2s[r]);
        if (gi == 0) h2cur[(size_t)(rbase + r) * HH + jg] = hv;
      }
    }

    // ----- L1[t+1]: z1 = x[t+1] @ Wi1 + h1[t] @ Wh1 + b1 -----
    if (t < TT - 1) {
      f32x4 accA = {bias1, bias1, bias1, bias1};
      f32x4 accB = {0.f, 0.f, 0.f, 0.f}, accC = {0.f, 0.f, 0.f, 0.f};
      __syncthreads(); STAGE_L1(0, t + 1, h1cur, KC); __syncthreads(); MFMA_CHUNK(wB1h, wB1l, 0, 4);
      __syncthreads(); STAGE_L1(1, t + 1, h1cur, KC); __syncthreads(); MFMA_CHUNK(wB1h, wB1l, 128, 4);
      __syncthreads(); STAGE_L1(2, t + 1, h1cur, 96); __syncthreads(); MFMA_CHUNK(wB1h, wB1l, 256, 3);
      f32x4 z = accA + accB + accC;
#pragma unroll
      for (int r = 0; r < 4; ++r) {
        float zr = z[r];
        float s1 = __shfl_xor(zr, 1), s2 = __shfl_xor(zr, 2), s3 = __shfl_xor(zr, 3);
        float g0 = pick4(gi, zr, s1, s2, s3);
        float g1 = pick4(gi ^ 1, zr, s1, s2, s3);
        float g2 = pick4(gi ^ 2, zr, s1, s2, s3);
        float g3 = pick4(gi ^ 3, zr, s1, s2, s3);
        float ig = sigm(g0), fg = sigm(g1), gg = tanh_f(g2), og = sigm(g3);
        c1s[r] = fg * c1s[r] + ig * gg;
        float hv = og * tanh_f(c1s[r]);
        if (gi == 0) h1nxt[(size_t)(rbase + r) * HH + jg] = hv;
      }
    }
    grid.sync();
  }

  // ---- dense head: logits = h2[511] @ Wd + bd ; h2[511] is slot 1 ----
  if (tid < 2 * NC) {
    int r = blockIdx.x * 2 + tid / NC;
    int n = tid % NC;
    float s = bd[n];
    const float* f = h2buf + BBHH + (size_t)r * HH;
#pragma unroll 8
    for (int k = 0; k < HH; ++k) s += f[k] * Wd[k * NC + n];
    out[r * NC + n] = s;
  }
}

extern "C" void kernel_launch(void* const* d_in, const int* in_sizes, int n_in,
                              void* d_out, int out_size, void* d_ws, size_t ws_size,
                              hipStream_t stream) {
  const float* x   = (const float*)d_in[0];
  const float* Wi1 = (const float*)d_in[1];
  const float* Wh1 = (const float*)d_in[2];
  const float* b1  = (const float*)d_in[3];
  const float* Wi2 = (const float*)d_in[4];
  const float* Wh2 = (const float*)d_in[5];
  const float* b2  = (const float*)d_in[6];
  const float* Wd  = (const float*)d_in[7];
  const float* bd  = (const float*)d_in[8];

  char* ws = (char*)d_ws;
  // ws layout (bytes), total 5,636,096 (~5.4 MB):
  //   [0, 1MB)        h1 ping-pong fp32 [2][512][256]
  //   [1MB, 2MB)      h2 ping-pong fp32
  //   [2MB, ..)       w1hg / w1lg: bf16 [1024][352] each (720,896 B each)
  //   then            w2hg / w2lg: bf16 [1024][512] each (1,048,576 B each)
  float* h1 = (float*)(ws);
  float* h2 = (float*)(ws + 1048576u);
  u16* w1hg = (u16*)(ws + 2097152u);
  u16* w1lg = (u16*)(ws + 2097152u + 720896u);
  u16* w2hg = (u16*)(ws + 2097152u + 2u * 720896u);
  u16* w2lg = (u16*)(ws + 2097152u + 2u * 720896u + 1048576u);
  float* out = (float*)d_out;

  const int total = 1024 * K1 + 1024 * K2;   // 884,736
  repack_kernel<<<(total + 255) / 256, 256, 0, stream>>>(
      Wi1, Wh1, Wi2, Wh2, w1hg, w1lg, w2hg, w2lg);

  void* args[] = {
    (void*)&x, (void*)&b1, (void*)&b2, (void*)&Wd, (void*)&bd,
    (void*)&w1hg, (void*)&w1lg, (void*)&w2hg, (void*)&w2lg,
    (void*)&h1, (void*)&h2, (void*)&out
  };
  (void)hipLaunchCooperativeKernel((void*)lstm_kernel, dim3(NBLK),
                                   dim3(NTHREADS), args, 0, stream);
}

// Round 7
// 17792.973 us; speedup vs baseline: 4.4828x; 1.5293x over previous
//
#include <hip/hip_runtime.h>
#include <hip/hip_cooperative_groups.h>

#define BB 512
#define TT 512
#define DD 76
#define HH 256
#define NC 25
#define NBLK 256
#define NTHREADS 512
#define BBHH (BB * HH)

#define K1 352      // L1 virtual K: 76 x | 256 h | 20 zero-pad (multiple of 32)
#define K2 512      // L2 K: 256 h1 | 256 h2
#define WS1 360     // LDS k-stride (u16) for W1 planes
#define WS2 520     // LDS k-stride (u16) for W2 planes
#define ACT_S 136   // LDS act row stride (u16)
#define KC 128      // act chunk width

typedef unsigned short u16;
typedef unsigned int u32;
typedef __attribute__((ext_vector_type(8))) short bf16x8;
typedef __attribute__((ext_vector_type(4))) float f32x4;

__device__ __forceinline__ float bf2f(u16 v) {
  union { u32 u; float f; } c; c.u = ((u32)v) << 16; return c.f;
}
__device__ __forceinline__ u16 f2bf(float f) {
  union { u32 u; float f; } c; c.f = f;
  u32 r = c.u + 0x7FFFu + ((c.u >> 16) & 1u);   // RNE
  return (u16)(r >> 16);
}
__device__ __forceinline__ void split2(float f, u16& h, u16& l) {
  u16 hh = f2bf(f);
  float r = f - bf2f(hh);
  h = hh; l = f2bf(r);
}
__device__ __forceinline__ float sigm(float v) { return 1.0f / (1.0f + __expf(-v)); }
__device__ __forceinline__ float tanh_f(float v) {
  float e = __expf(2.0f * v);
  return 1.0f - 2.0f / (e + 1.0f);
}
__device__ __forceinline__ float pick4(int m, float a, float b, float c, float d) {
  return m == 0 ? a : (m == 1 ? b : (m == 2 ? c : d));
}

// ---- 32-block group barrier: slot = [count, gen] on its own 256B line ----
// Correct under any block->XCD mapping: device-scope atomics; release via the
// ACQ_REL arrival RMW (preceded by __syncthreads' per-wave vmcnt drain),
// acquire via fence on exit. Co-residency guaranteed by cooperative launch.
__device__ __forceinline__ void group_bar(u32* slot) {
  __syncthreads();
  if (threadIdx.x == 0) {
    u32 gen = __hip_atomic_load(slot + 1, __ATOMIC_RELAXED, __HIP_MEMORY_SCOPE_AGENT);
    u32 prev = __hip_atomic_fetch_add(slot, 1u, __ATOMIC_ACQ_REL, __HIP_MEMORY_SCOPE_AGENT);
    if (prev == 31u) {
      __hip_atomic_store(slot, 0u, __ATOMIC_RELAXED, __HIP_MEMORY_SCOPE_AGENT);
      __hip_atomic_store(slot + 1, gen + 1u, __ATOMIC_RELEASE, __HIP_MEMORY_SCOPE_AGENT);
    } else {
      while (__hip_atomic_load(slot + 1, __ATOMIC_RELAXED, __HIP_MEMORY_SCOPE_AGENT) == gen)
        __builtin_amdgcn_s_sleep(1);
    }
    __builtin_amdgcn_fence(__ATOMIC_ACQUIRE, "agent");
  }
  __syncthreads();
}

// ---- repack: fp32 [k][4H] -> hi/lo bf16 planes, layout [c=4j+g][k] with L1 zero-pad ----
__global__ void repack_kernel(const float* __restrict__ Wi1, const float* __restrict__ Wh1,
                              const float* __restrict__ Wi2, const float* __restrict__ Wh2,
                              u16* __restrict__ w1hg, u16* __restrict__ w1lg,
                              u16* __restrict__ w2hg, u16* __restrict__ w2lg) {
  int idx = blockIdx.x * blockDim.x + threadIdx.x;
  const int N1 = 1024 * K1;
  if (idx < N1) {
    int c = idx / K1, k = idx - c * K1;
    int src = (c & 3) * HH + (c >> 2);
    float v = 0.f;
    if (k < DD) v = Wi1[k * 1024 + src];
    else if (k < DD + HH) v = Wh1[(k - DD) * 1024 + src];
    u16 h, l; split2(v, h, l);
    w1hg[idx] = h; w1lg[idx] = l;
  } else if (idx < N1 + 1024 * K2) {
    int d = idx - N1;
    int c = d >> 9, k = d & 511;
    int src = (c & 3) * HH + (c >> 2);
    float v = (k < HH) ? Wi2[k * 1024 + src] : Wh2[(k - HH) * 1024 + src];
    u16 h, l; split2(v, h, l);
    w2hg[d] = h; w2lg[d] = l;
  }
}

// stage a 128-wide act chunk from an h-buffer (rows of HH floats), split hi/lo
#define STAGE_H128(srcbase, kofs)                                                  \
  for (int i = tid; i < 64 * 32; i += NTHREADS) {                                  \
    int r_ = i >> 5, c4_ = i & 31;                                                 \
    float4 v_ = *(const float4*)((srcbase) + (size_t)(row0 + r_) * HH + (kofs) + c4_ * 4); \
    u16 h0_, l0_, h1_, l1_, h2_, l2_, h3_, l3_;                                    \
    split2(v_.x, h0_, l0_); split2(v_.y, h1_, l1_);                                \
    split2(v_.z, h2_, l2_); split2(v_.w, h3_, l3_);                                \
    *(ushort4*)&ath[r_ * ACT_S + c4_ * 4] = make_ushort4(h0_, h1_, h2_, h3_);      \
    *(ushort4*)&atl[r_ * ACT_S + c4_ * 4] = make_ushort4(l0_, l1_, l2_, l3_);      \
  }

// stage an L1 act chunk: k<76 -> x[.,tt,.]; 76..331 -> h1src (or 0); else 0
#define STAGE_L1(chunk, tt, h1src, width)                                          \
  for (int i = tid; i < 64 * (width); i += NTHREADS) {                             \
    int r_ = i / (width), kk_ = i - r_ * (width);                                  \
    int kv_ = (chunk) * KC + kk_;                                                  \
    float v_ = 0.f;                                                                \
    if (kv_ < DD) v_ = x[((size_t)(row0 + r_) * TT + (tt)) * DD + kv_];            \
    else if (kv_ < DD + HH && (h1src) != nullptr)                                  \
      v_ = ((const float*)(h1src))[(size_t)(row0 + r_) * HH + kv_ - DD];           \
    u16 hh_, ll_; split2(v_, hh_, ll_);                                            \
    ath[r_ * ACT_S + kk_] = hh_; atl[r_ * ACT_S + kk_] = ll_;                      \
  }

// 3-term split-fp32 MFMA over one staged chunk
#define MFMA_CHUNK(Bh, Bl, wofs, nks)                                              \
  for (int s_ = 0; s_ < (nks); ++s_) {                                             \
    const int ko_ = s_ * 32 + qd * 8;                                              \
    bf16x8 a_h = *(const bf16x8*)(wA + ko_);                                       \
    bf16x8 a_l = *(const bf16x8*)(wAl + ko_);                                      \
    bf16x8 b_h = *(const bf16x8*)((Bh) + (wofs) + ko_);                            \
    bf16x8 b_l = *(const bf16x8*)((Bl) + (wofs) + ko_);                            \
    accA = __builtin_amdgcn_mfma_f32_16x16x32_bf16(a_h, b_h, accA, 0, 0, 0);       \
    accB = __builtin_amdgcn_mfma_f32_16x16x32_bf16(a_h, b_l, accB, 0, 0, 0);       \
    accC = __builtin_amdgcn_mfma_f32_16x16x32_bf16(a_l, b_h, accC, 0, 0, 0);       \
  }

#define GATES_UPDATE(Z, CS, DST)                                                   \
  _Pragma("unroll")                                                                \
  for (int r = 0; r < 4; ++r) {                                                    \
    float zr = (Z)[r];                                                             \
    float s1 = __shfl_xor(zr, 1), s2 = __shfl_xor(zr, 2), s3 = __shfl_xor(zr, 3);  \
    float g0 = pick4(gi, zr, s1, s2, s3);                                          \
    float g1 = pick4(gi ^ 1, zr, s1, s2, s3);                                      \
    float g2 = pick4(gi ^ 2, zr, s1, s2, s3);                                      \
    float g3 = pick4(gi ^ 3, zr, s1, s2, s3);                                      \
    float ig = sigm(g0), fg = sigm(g1), gg = tanh_f(g2), og = sigm(g3);            \
    (CS)[r] = fg * (CS)[r] + ig * gg;                                              \
    float hv = og * tanh_f((CS)[r]);                                               \
    if (gi == 0) (DST)[(size_t)(rbase + r) * HH + jg] = hv;                        \
  }

__global__ __launch_bounds__(NTHREADS) void lstm_kernel(
    const float* __restrict__ x,
    const float* __restrict__ b1, const float* __restrict__ b2,
    const float* __restrict__ Wd, const float* __restrict__ bd,
    const u16* __restrict__ w1hg, const u16* __restrict__ w1lg,
    const u16* __restrict__ w2hg, const u16* __restrict__ w2lg,
    float* __restrict__ h1buf, float* __restrict__ h2buf,
    u32* __restrict__ barbase,
    float* __restrict__ out)
{
  __shared__ u16 w1h[32 * WS1], w1l[32 * WS1];     // 46,080 B
  __shared__ u16 w2h[32 * WS2], w2l[32 * WS2];     // 66,560 B
  __shared__ u16 ath[64 * ACT_S], atl[64 * ACT_S]; // 34,816 B  (total 147,456)

  const int tid = threadIdx.x;
  const int lane = tid & 63;
  const int wv = tid >> 6;            // 0..7
  const int mf = wv & 3;              // M-frag: rows mf*16..
  const int nf = wv >> 2;             // 0..1: cols nf*16..
  const int nl = lane & 15;
  const int qd = lane >> 4;           // 0..3
  const int bt = blockIdx.x & 7;      // row-group; group members share only this
  const int jt = blockIdx.x >> 3;     // 0..31 col-group (= local index within group)
  const int row0 = bt * 64;
  u32* bslot = barbase + bt * 64;     // 256B-separated per-group barrier line

  // ---- stage weight slices to LDS once (u32 copies) ----
  for (int i = tid; i < 32 * (K1 / 2); i += NTHREADS) {      // 176 u32 per col
    int c = i / 176, kk = i - c * 176;
    ((u32*)&w1h[c * WS1])[kk] = ((const u32*)(w1hg + (size_t)(jt * 32 + c) * K1))[kk];
    ((u32*)&w1l[c * WS1])[kk] = ((const u32*)(w1lg + (size_t)(jt * 32 + c) * K1))[kk];
  }
  for (int i = tid; i < 32 * (K2 / 2); i += NTHREADS) {      // 256 u32 per col
    int c = i >> 8, kk = i & 255;
    ((u32*)&w2h[c * WS2])[kk] = ((const u32*)(w2hg + (size_t)(jt * 32 + c) * K2))[kk];
    ((u32*)&w2l[c * WS2])[kk] = ((const u32*)(w2lg + (size_t)(jt * 32 + c) * K2))[kk];
  }

  const int cg_col = jt * 32 + nf * 16 + nl;   // global gate-col 0..1023
  const int jg = cg_col >> 2;                  // hidden unit
  const int gi = cg_col & 3;                   // this lane's gate
  const float bias1 = b1[gi * HH + jg];
  const float bias2 = b2[gi * HH + jg];
  const int rbase = row0 + mf * 16 + qd * 4;   // first of this lane's 4 D rows
  float c1s[4] = {0.f, 0.f, 0.f, 0.f}, c2s[4] = {0.f, 0.f, 0.f, 0.f};

  const u16* wA  = ath + (mf * 16 + nl) * ACT_S;   // A-frag row base (hi)
  const u16* wAl = atl + (mf * 16 + nl) * ACT_S;   // (lo)
  const int cl = nf * 16 + nl;                     // local col 0..31
  const u16* wB1h = w1h + cl * WS1;
  const u16* wB1l = w1l + cl * WS1;
  const u16* wB2h = w2h + cl * WS2;
  const u16* wB2l = w2l + cl * WS2;

  // ---- prologue: h1[0] = L1(x[0], h1[-1]=0); only chunk 0 is non-zero ----
  {
    f32x4 accA = {bias1, bias1, bias1, bias1};
    f32x4 accB = {0.f, 0.f, 0.f, 0.f}, accC = {0.f, 0.f, 0.f, 0.f};
    __syncthreads();
    STAGE_L1(0, 0, (const float*)nullptr, KC);
    __syncthreads();
    MFMA_CHUNK(wB1h, wB1l, 0, 4);
    f32x4 z = accA + accB + accC;
    GATES_UPDATE(z, c1s, h1buf);   // slot 0
  }
  group_bar(bslot);

  // ---- main loop: phase t computes L2[t] and L1[t+1]; one group barrier per phase ----
#pragma unroll 1
  for (int t = 0; t < TT; ++t) {
    const float* h1cur = h1buf + (t & 1) * BBHH;
    float* h1nxt = h1buf + ((t + 1) & 1) * BBHH;
    const float* h2prv = h2buf + ((t + 1) & 1) * BBHH;   // == (t-1)&1
    float* h2cur = h2buf + (t & 1) * BBHH;

    // ----- L2[t]: z2 = h1[t] @ Wi2 + h2[t-1] @ Wh2 + b2 -----
    {
      f32x4 accA = {bias2, bias2, bias2, bias2};
      f32x4 accB = {0.f, 0.f, 0.f, 0.f}, accC = {0.f, 0.f, 0.f, 0.f};
      __syncthreads(); STAGE_H128(h1cur, 0);   __syncthreads(); MFMA_CHUNK(wB2h, wB2l, 0, 4);
      __syncthreads(); STAGE_H128(h1cur, 128); __syncthreads(); MFMA_CHUNK(wB2h, wB2l, 128, 4);
      if (t > 0) {
        __syncthreads(); STAGE_H128(h2prv, 0);   __syncthreads(); MFMA_CHUNK(wB2h, wB2l, 256, 4);
        __syncthreads(); STAGE_H128(h2prv, 128); __syncthreads(); MFMA_CHUNK(wB2h, wB2l, 384, 4);
      }
      f32x4 z = accA + accB + accC;
      GATES_UPDATE(z, c2s, h2cur);
    }

    // ----- L1[t+1]: z1 = x[t+1] @ Wi1 + h1[t] @ Wh1 + b1 -----
    if (t < TT - 1) {
      f32x4 accA = {bias1, bias1, bias1, bias1};
      f32x4 accB = {0.f, 0.f, 0.f, 0.f}, accC = {0.f, 0.f, 0.f, 0.f};
      __syncthreads(); STAGE_L1(0, t + 1, h1cur, KC); __syncthreads(); MFMA_CHUNK(wB1h, wB1l, 0, 4);
      __syncthreads(); STAGE_L1(1, t + 1, h1cur, KC); __syncthreads(); MFMA_CHUNK(wB1h, wB1l, 128, 4);
      __syncthreads(); STAGE_L1(2, t + 1, h1cur, 96); __syncthreads(); MFMA_CHUNK(wB1h, wB1l, 256, 3);
      f32x4 z = accA + accB + accC;
      GATES_UPDATE(z, c1s, h1nxt);
    }
    group_bar(bslot);
  }

  // ---- dense head (group-local rows): logits = h2[511] @ Wd + bd ; slot 1 ----
  if (tid < 2 * NC) {
    int r = row0 + jt * 2 + tid / NC;
    int n = tid % NC;
    float s = bd[n];
    const float* f = h2buf + BBHH + (size_t)r * HH;
#pragma unroll 8
    for (int k = 0; k < HH; ++k) s += f[k] * Wd[k * NC + n];
    out[r * NC + n] = s;
  }
}

extern "C" void kernel_launch(void* const* d_in, const int* in_sizes, int n_in,
                              void* d_out, int out_size, void* d_ws, size_t ws_size,
                              hipStream_t stream) {
  const float* x   = (const float*)d_in[0];
  const float* Wi1 = (const float*)d_in[1];
  const float* Wh1 = (const float*)d_in[2];
  const float* b1  = (const float*)d_in[3];
  const float* Wi2 = (const float*)d_in[4];
  const float* Wh2 = (const float*)d_in[5];
  const float* b2  = (const float*)d_in[6];
  const float* Wd  = (const float*)d_in[7];
  const float* bd  = (const float*)d_in[8];

  char* ws = (char*)d_ws;
  // ws layout (bytes), total 5,638,144 (~5.38 MiB):
  //   [0, 1MB)        h1 ping-pong fp32 [2][512][256]
  //   [1MB, 2MB)      h2 ping-pong fp32
  //   [2MB, ..)       w1hg / w1lg: bf16 [1024][352] each (720,896 B each)
  //   then            w2hg / w2lg: bf16 [1024][512] each (1,048,576 B each)
  //   [5,636,096, +2KB)  8 group-barrier slots, 256 B apart (zeroed every call)
  float* h1 = (float*)(ws);
  float* h2 = (float*)(ws + 1048576u);
  u16* w1hg = (u16*)(ws + 2097152u);
  u16* w1lg = (u16*)(ws + 2097152u + 720896u);
  u16* w2hg = (u16*)(ws + 2097152u + 2u * 720896u);
  u16* w2lg = (u16*)(ws + 2097152u + 2u * 720896u + 1048576u);
  u32* bar  = (u32*)(ws + 5636096u);
  float* out = (float*)d_out;

  hipMemsetAsync((void*)bar, 0, 2048, stream);
  const int total = 1024 * K1 + 1024 * K2;   // 884,736
  repack_kernel<<<(total + 255) / 256, 256, 0, stream>>>(
      Wi1, Wh1, Wi2, Wh2, w1hg, w1lg, w2hg, w2lg);

  void* args[] = {
    (void*)&x, (void*)&b1, (void*)&b2, (void*)&Wd, (void*)&bd,
    (void*)&w1hg, (void*)&w1lg, (void*)&w2hg, (void*)&w2lg,
    (void*)&h1, (void*)&h2, (void*)&bar, (void*)&out
  };
  // Cooperative launch purely for the co-residency guarantee; sync is custom.
  (void)hipLaunchCooperativeKernel((void*)lstm_kernel, dim3(NBLK),
                                   dim3(NTHREADS), args, 0, stream);
}

// Round 8
// 13575.464 us; speedup vs baseline: 5.8754x; 1.3107x over previous
//
#include <hip/hip_runtime.h>
#include <hip/hip_cooperative_groups.h>

#define BB 512
#define TT 512
#define DD 76
#define HH 256
#define NC 25
#define NBLK 256
#define NTHREADS 512
#define BBHH (BB * HH)

#define K1 352      // L1 virtual K: 76 x | 256 h | 20 zero-pad
#define K2 512      // L2 K: 256 h1 | 256 h2
#define WS1 360     // LDS k-stride (u16) for W1 planes
#define WS2 520     // LDS k-stride (u16) for W2 planes
#define ACT_S 136   // LDS act row stride (u16)

typedef unsigned short u16;
typedef unsigned int u32;
typedef __attribute__((ext_vector_type(8))) short bf16x8;
typedef __attribute__((ext_vector_type(4))) float f32x4;

__device__ __forceinline__ float bf2f(u16 v) {
  union { u32 u; float f; } c; c.u = ((u32)v) << 16; return c.f;
}
__device__ __forceinline__ u16 f2bf(float f) {
  union { u32 u; float f; } c; c.f = f;
  u32 r = c.u + 0x7FFFu + ((c.u >> 16) & 1u);   // RNE
  return (u16)(r >> 16);
}
__device__ __forceinline__ void split2(float f, u16& h, u16& l) {
  u16 hh = f2bf(f);
  float r = f - bf2f(hh);
  h = hh; l = f2bf(r);
}
__device__ __forceinline__ float sigm(float v) { return 1.0f / (1.0f + __expf(-v)); }
__device__ __forceinline__ float tanh_f(float v) {
  float e = __expf(2.0f * v);
  return 1.0f - 2.0f / (e + 1.0f);
}
__device__ __forceinline__ float pick4(int m, float a, float b, float c, float d) {
  return m == 0 ? a : (m == 1 ? b : (m == 2 ? c : d));
}

// ---- distributed flag sync: 32 flags/group, each on own 128B line ----
__device__ __forceinline__ void wait_flags(const u32* fbase, u32 target) {
  const int tid = threadIdx.x;
  if (tid < 32) {
    const u32* p = fbase + tid * 32;
    while (__hip_atomic_load(p, __ATOMIC_RELAXED, __HIP_MEMORY_SCOPE_AGENT) < target)
      __builtin_amdgcn_s_sleep(1);
  }
  if (tid == 0) __builtin_amdgcn_fence(__ATOMIC_ACQUIRE, "agent");
  __syncthreads();
}
__device__ __forceinline__ void post_flag(u32* slot, u32 val) {
  __syncthreads();   // all waves' stores drained (vmcnt(0) before s_barrier)
  if (threadIdx.x == 0) {
    __builtin_amdgcn_fence(__ATOMIC_RELEASE, "agent");
    __hip_atomic_store(slot, val, __ATOMIC_RELAXED, __HIP_MEMORY_SCOPE_AGENT);
  }
}

// ---- repack: fp32 [k][4H] -> hi/lo bf16 planes, layout [c=4j+g][k], L1 zero-pad ----
__global__ void repack_kernel(const float* __restrict__ Wi1, const float* __restrict__ Wh1,
                              const float* __restrict__ Wi2, const float* __restrict__ Wh2,
                              u16* __restrict__ w1hg, u16* __restrict__ w1lg,
                              u16* __restrict__ w2hg, u16* __restrict__ w2lg) {
  int idx = blockIdx.x * blockDim.x + threadIdx.x;
  const int N1 = 1024 * K1;
  if (idx < N1) {
    int c = idx / K1, k = idx - c * K1;
    int src = (c & 3) * HH + (c >> 2);
    float v = 0.f;
    if (k < DD) v = Wi1[k * 1024 + src];
    else if (k < DD + HH) v = Wh1[(k - DD) * 1024 + src];
    u16 h, l; split2(v, h, l);
    w1hg[idx] = h; w1lg[idx] = l;
  } else if (idx < N1 + 1024 * K2) {
    int d = idx - N1;
    int c = d >> 9, k = d & 511;
    int src = (c & 3) * HH + (c >> 2);
    float v = (k < HH) ? Wi2[k * 1024 + src] : Wh2[(k - HH) * 1024 + src];
    u16 h, l; split2(v, h, l);
    w2hg[d] = h; w2lg[d] = l;
  }
}

// prefetch a full 128-wide pre-split h chunk into regs (4 uint2 per plane)
#define PF_H(HI, LO, KOFS)                                                         \
  _Pragma("unroll")                                                                \
  for (int k_ = 0; k_ < 4; ++k_) {                                                 \
    int i_ = tid + k_ * NTHREADS;                                                  \
    int r_ = i_ >> 5, c_ = i_ & 31;                                                \
    pfh[k_] = *(const uint2*)((HI) + (size_t)(row0 + r_) * HH + (KOFS) + c_ * 4);  \
    pfl[k_] = *(const uint2*)((LO) + (size_t)(row0 + r_) * HH + (KOFS) + c_ * 4);  \
  }
#define WR_H()                                                                     \
  _Pragma("unroll")                                                                \
  for (int k_ = 0; k_ < 4; ++k_) {                                                 \
    int i_ = tid + k_ * NTHREADS;                                                  \
    int r_ = i_ >> 5, c_ = i_ & 31;                                                \
    *(uint2*)&ath[r_ * ACT_S + c_ * 4] = pfh[k_];                                  \
    *(uint2*)&atl[r_ * ACT_S + c_ * 4] = pfl[k_];                                  \
  }

// L1 chunk0: x[t] fp32 (split here) in cols 0..75, h1[0..51] (pre-split) in 76..127
#define STAGE_C0(TTT, H1H, H1L)                                                    \
  for (int i_ = tid; i_ < 64 * 19; i_ += NTHREADS) {                               \
    int r_ = i_ / 19, c_ = i_ - r_ * 19;                                           \
    float4 v_ = *(const float4*)(x + ((size_t)(row0 + r_) * TT + (TTT)) * DD + c_ * 4); \
    u16 h0_, l0_, h1_, l1_, h2_, l2_, h3_, l3_;                                    \
    split2(v_.x, h0_, l0_); split2(v_.y, h1_, l1_);                                \
    split2(v_.z, h2_, l2_); split2(v_.w, h3_, l3_);                                \
    *(ushort4*)&ath[r_ * ACT_S + c_ * 4] = make_ushort4(h0_, h1_, h2_, h3_);       \
    *(ushort4*)&atl[r_ * ACT_S + c_ * 4] = make_ushort4(l0_, l1_, l2_, l3_);       \
  }                                                                                \
  for (int i_ = tid; i_ < 64 * 13; i_ += NTHREADS) {                               \
    int r_ = i_ / 13, c_ = i_ - r_ * 13;                                           \
    uint2 vh_ = make_uint2(0u, 0u), vl_ = make_uint2(0u, 0u);                      \
    if ((H1H) != nullptr) {                                                        \
      vh_ = *(const uint2*)((H1H) + (size_t)(row0 + r_) * HH + c_ * 4);            \
      vl_ = *(const uint2*)((H1L) + (size_t)(row0 + r_) * HH + c_ * 4);            \
    }                                                                              \
    *(uint2*)&ath[r_ * ACT_S + 76 + c_ * 4] = vh_;                                 \
    *(uint2*)&atl[r_ * ACT_S + 76 + c_ * 4] = vl_;                                 \
  }

// L1 chunk2: h1[180..255] in cols 0..75, zeros in 76..127 (zero-weight pad rows)
#define STAGE_C2(H1H, H1L)                                                         \
  for (int i_ = tid; i_ < 64 * 32; i_ += NTHREADS) {                               \
    int r_ = i_ >> 5, c_ = i_ & 31;                                                \
    uint2 vh_ = make_uint2(0u, 0u), vl_ = make_uint2(0u, 0u);                      \
    if (c_ < 19) {                                                                 \
      vh_ = *(const uint2*)((H1H) + (size_t)(row0 + r_) * HH + 180 + c_ * 4);      \
      vl_ = *(const uint2*)((H1L) + (size_t)(row0 + r_) * HH + 180 + c_ * 4);      \
    }                                                                              \
    *(uint2*)&ath[r_ * ACT_S + c_ * 4] = vh_;                                      \
    *(uint2*)&atl[r_ * ACT_S + c_ * 4] = vl_;                                      \
  }

// 3-term split-fp32 MFMA over one staged 128-wide chunk
#define MFMA_CHUNK(Bh, Bl, wofs, nks)                                              \
  for (int s_ = 0; s_ < (nks); ++s_) {                                             \
    const int ko_ = s_ * 32 + qd * 8;                                              \
    bf16x8 a_h = *(const bf16x8*)(wA + ko_);                                       \
    bf16x8 a_l = *(const bf16x8*)(wAl + ko_);                                      \
    bf16x8 b_h = *(const bf16x8*)((Bh) + (wofs) + ko_);                            \
    bf16x8 b_l = *(const bf16x8*)((Bl) + (wofs) + ko_);                            \
    accA = __builtin_amdgcn_mfma_f32_16x16x32_bf16(a_h, b_h, accA, 0, 0, 0);       \
    accB = __builtin_amdgcn_mfma_f32_16x16x32_bf16(a_h, b_l, accB, 0, 0, 0);       \
    accC = __builtin_amdgcn_mfma_f32_16x16x32_bf16(a_l, b_h, accC, 0, 0, 0);       \
  }

#define GATES2(Z, CS, DH, DL)                                                      \
  _Pragma("unroll")                                                                \
  for (int r = 0; r < 4; ++r) {                                                    \
    float zr = (Z)[r];                                                             \
    float s1 = __shfl_xor(zr, 1), s2 = __shfl_xor(zr, 2), s3 = __shfl_xor(zr, 3);  \
    float g0 = pick4(gi, zr, s1, s2, s3);                                          \
    float g1 = pick4(gi ^ 1, zr, s1, s2, s3);                                      \
    float g2 = pick4(gi ^ 2, zr, s1, s2, s3);                                      \
    float g3 = pick4(gi ^ 3, zr, s1, s2, s3);                                      \
    float ig = sigm(g0), fg = sigm(g1), gg = tanh_f(g2), og = sigm(g3);            \
    (CS)[r] = fg * (CS)[r] + ig * gg;                                              \
    float hv = og * tanh_f((CS)[r]);                                               \
    if (gi == 0) {                                                                 \
      u16 hh_, hl_; split2(hv, hh_, hl_);                                          \
      (DH)[(size_t)(rbase + r) * HH + jg] = hh_;                                   \
      (DL)[(size_t)(rbase + r) * HH + jg] = hl_;                                   \
    }                                                                              \
  }

__global__ __launch_bounds__(NTHREADS) void lstm_kernel(
    const float* __restrict__ x,
    const float* __restrict__ b1, const float* __restrict__ b2,
    const float* __restrict__ Wd, const float* __restrict__ bd,
    const u16* __restrict__ w1hg, const u16* __restrict__ w1lg,
    const u16* __restrict__ w2hg, const u16* __restrict__ w2lg,
    u16* __restrict__ h1h, u16* __restrict__ h1l,
    u16* __restrict__ h2h, u16* __restrict__ h2l,
    u32* __restrict__ flags,
    float* __restrict__ out)
{
  __shared__ u16 w1h[32 * WS1], w1l[32 * WS1];     // 46,080 B
  __shared__ u16 w2h[32 * WS2], w2l[32 * WS2];     // 66,560 B
  __shared__ u16 ath[64 * ACT_S], atl[64 * ACT_S]; // 34,816 B (total 147,456)

  const int tid = threadIdx.x;
  const int lane = tid & 63;
  const int wv = tid >> 6;            // 0..7
  const int mf = wv & 3;              // M-frag: rows mf*16..
  const int nf = wv >> 2;             // 0..1: cols nf*16..
  const int nl = lane & 15;
  const int qd = lane >> 4;           // 0..3
  const int bt = blockIdx.x & 7;      // row-group (likely XCD-aligned via %8 dispatch)
  const int jt = blockIdx.x >> 3;     // 0..31 col-group within the group
  const int row0 = bt * 64;

  u32* gAp = flags + bt * 1024;                 // poll bases (32 flags x 32-u32 spacing)
  u32* gBp = flags + 8192 + bt * 1024;
  u32* gAslot = gAp + jt * 32;                  // this block's flags
  u32* gBslot = gBp + jt * 32;

  // ---- stage weight slices to LDS once ----
  for (int i = tid; i < 32 * (K1 / 2); i += NTHREADS) {
    int c = i / 176, kk = i - c * 176;
    ((u32*)&w1h[c * WS1])[kk] = ((const u32*)(w1hg + (size_t)(jt * 32 + c) * K1))[kk];
    ((u32*)&w1l[c * WS1])[kk] = ((const u32*)(w1lg + (size_t)(jt * 32 + c) * K1))[kk];
  }
  for (int i = tid; i < 32 * (K2 / 2); i += NTHREADS) {
    int c = i >> 8, kk = i & 255;
    ((u32*)&w2h[c * WS2])[kk] = ((const u32*)(w2hg + (size_t)(jt * 32 + c) * K2))[kk];
    ((u32*)&w2l[c * WS2])[kk] = ((const u32*)(w2lg + (size_t)(jt * 32 + c) * K2))[kk];
  }

  const int cg_col = jt * 32 + nf * 16 + nl;
  const int jg = cg_col >> 2;
  const int gi = cg_col & 3;
  const float bias1 = b1[gi * HH + jg];
  const float bias2 = b2[gi * HH + jg];
  const int rbase = row0 + mf * 16 + qd * 4;
  float c1s[4] = {0.f, 0.f, 0.f, 0.f}, c2s[4] = {0.f, 0.f, 0.f, 0.f};

  const u16* wA  = ath + (mf * 16 + nl) * ACT_S;
  const u16* wAl = atl + (mf * 16 + nl) * ACT_S;
  const int cl = nf * 16 + nl;
  const u16* wB1h = w1h + cl * WS1;
  const u16* wB1l = w1l + cl * WS1;
  const u16* wB2h = w2h + cl * WS2;
  const u16* wB2l = w2l + cl * WS2;

  // ---- prologue: h1[0] = L1(x[0], 0) -> slot 0; post A=1, B=1 ----
  {
    f32x4 accA = {bias1, bias1, bias1, bias1};
    f32x4 accB = {0.f, 0.f, 0.f, 0.f}, accC = {0.f, 0.f, 0.f, 0.f};
    STAGE_C0(0, (const u16*)nullptr, (const u16*)nullptr);
    __syncthreads();   // orders weight + act LDS writes before reads
    MFMA_CHUNK(wB1h, wB1l, 0, 4);
    f32x4 z = accA + accB + accC;
    GATES2(z, c1s, h1h, h1l);
    __syncthreads();
    if (tid == 0) {
      __builtin_amdgcn_fence(__ATOMIC_RELEASE, "agent");
      __hip_atomic_store(gAslot, 1u, __ATOMIC_RELAXED, __HIP_MEMORY_SCOPE_AGENT);
      __hip_atomic_store(gBslot, 1u, __ATOMIC_RELAXED, __HIP_MEMORY_SCOPE_AGENT);
    }
  }

  // ---- main loop: phase t = L2[t] then L1[t+1] ----
#pragma unroll 1
  for (int t = 0; t < TT; ++t) {
    const u16* h1ch = h1h + (t & 1) * BBHH;        // h1[t]
    const u16* h1cl = h1l + (t & 1) * BBHH;
    u16* h1nh = h1h + ((t + 1) & 1) * BBHH;        // h1[t+1]
    u16* h1nl = h1l + ((t + 1) & 1) * BBHH;
    const u16* h2ph_ = h2h + ((t + 1) & 1) * BBHH; // h2[t-1]
    const u16* h2pl_ = h2l + ((t + 1) & 1) * BBHH;
    u16* h2chp = h2h + (t & 1) * BBHH;             // h2[t]
    u16* h2clp = h2l + (t & 1) * BBHH;

    uint2 pfh[4], pfl[4];

    // ----- L2[t] -----
    {
      f32x4 accA = {bias2, bias2, bias2, bias2};
      f32x4 accB = {0.f, 0.f, 0.f, 0.f}, accC = {0.f, 0.f, 0.f, 0.f};
      wait_flags(gAp, t + 1);                       // h2[t-1] ready; h2-slot write-safe
      if (t > 0) {
        PF_H(h2ph_, h2pl_, 0);
        WR_H();
        PF_H(h2ph_, h2pl_, 128);
        __syncthreads();
        MFMA_CHUNK(wB2h, wB2l, 256, 4);             // h2 terms
        __syncthreads();
        WR_H();
        wait_flags(gBp, t + 1);                     // h1[t] ready (sync publishes WR)
        PF_H(h1ch, h1cl, 0);
        MFMA_CHUNK(wB2h, wB2l, 384, 4);
        __syncthreads();
        WR_H();
        PF_H(h1ch, h1cl, 128);
        __syncthreads();
        MFMA_CHUNK(wB2h, wB2l, 0, 4);               // h1 terms
        __syncthreads();
        WR_H();
        __syncthreads();
        MFMA_CHUNK(wB2h, wB2l, 128, 4);
      } else {
        wait_flags(gBp, 1);
        PF_H(h1ch, h1cl, 0);
        WR_H();
        PF_H(h1ch, h1cl, 128);
        __syncthreads();
        MFMA_CHUNK(wB2h, wB2l, 0, 4);
        __syncthreads();
        WR_H();
        __syncthreads();
        MFMA_CHUNK(wB2h, wB2l, 128, 4);
      }
      f32x4 z = accA + accB + accC;
      GATES2(z, c2s, h2chp, h2clp);
      post_flag(gAslot, t + 2);                     // internal sync also fences act reuse
    }

    // ----- L1[t+1] -----
    if (t < TT - 1) {
      f32x4 accA = {bias1, bias1, bias1, bias1};
      f32x4 accB = {0.f, 0.f, 0.f, 0.f}, accC = {0.f, 0.f, 0.f, 0.f};
      STAGE_C0(t + 1, h1ch, h1cl);
      PF_H(h1ch, h1cl, 52);                         // chunk1 = h1[52..179]
      __syncthreads();
      MFMA_CHUNK(wB1h, wB1l, 0, 4);
      __syncthreads();
      WR_H();
      __syncthreads();
      MFMA_CHUNK(wB1h, wB1l, 128, 4);
      __syncthreads();
      STAGE_C2(h1ch, h1cl);                         // h1[180..255] + zero pad
      __syncthreads();
      MFMA_CHUNK(wB1h, wB1l, 256, 3);
      f32x4 z = accA + accB + accC;
      GATES2(z, c1s, h1nh, h1nl);
      post_flag(gBslot, t + 2);
    }
  }

  // ---- dense head: logits = h2[511] @ Wd + bd (slot 1) ----
  wait_flags(gAp, TT + 1);
  if (tid < 2 * NC) {
    int r = row0 + jt * 2 + tid / NC;
    int n = tid - (tid / NC) * NC;
    float s = bd[n];
    const u16* fh = h2h + BBHH + (size_t)r * HH;
    const u16* fl = h2l + BBHH + (size_t)r * HH;
#pragma unroll 8
    for (int k = 0; k < HH; ++k)
      s += (bf2f(fh[k]) + bf2f(fl[k])) * Wd[k * NC + n];
    out[r * NC + n] = s;
  }
}

extern "C" void kernel_launch(void* const* d_in, const int* in_sizes, int n_in,
                              void* d_out, int out_size, void* d_ws, size_t ws_size,
                              hipStream_t stream) {
  const float* x   = (const float*)d_in[0];
  const float* Wi1 = (const float*)d_in[1];
  const float* Wh1 = (const float*)d_in[2];
  const float* b1  = (const float*)d_in[3];
  const float* Wi2 = (const float*)d_in[4];
  const float* Wh2 = (const float*)d_in[5];
  const float* b2  = (const float*)d_in[6];
  const float* Wd  = (const float*)d_in[7];
  const float* bd  = (const float*)d_in[8];

  char* ws = (char*)d_ws;
  // ws layout (bytes), total 5,701,632 (~5.44 MiB):
  //   [0, 512K)        h1h ping-pong bf16-hi [2][512][256]
  //   [512K, 1M)       h1l
  //   [1M, 1.5M)       h2h
  //   [1.5M, 2M)       h2l
  //   [2M, ..)         w1hg/w1lg (720,896 each), w2hg/w2lg (1,048,576 each)
  //   [5,636,096, +64K) flag arrays A and B (zeroed every call)
  u16* h1h = (u16*)(ws);
  u16* h1l = (u16*)(ws + 524288u);
  u16* h2h = (u16*)(ws + 1048576u);
  u16* h2l = (u16*)(ws + 1572864u);
  u16* w1hg = (u16*)(ws + 2097152u);
  u16* w1lg = (u16*)(ws + 2097152u + 720896u);
  u16* w2hg = (u16*)(ws + 2097152u + 2u * 720896u);
  u16* w2lg = (u16*)(ws + 2097152u + 2u * 720896u + 1048576u);
  u32* flags = (u32*)(ws + 5636096u);
  float* out = (float*)d_out;

  hipMemsetAsync((void*)flags, 0, 65536, stream);
  const int total = 1024 * K1 + 1024 * K2;
  repack_kernel<<<(total + 255) / 256, 256, 0, stream>>>(
      Wi1, Wh1, Wi2, Wh2, w1hg, w1lg, w2hg, w2lg);

  void* args[] = {
    (void*)&x, (void*)&b1, (void*)&b2, (void*)&Wd, (void*)&bd,
    (void*)&w1hg, (void*)&w1lg, (void*)&w2hg, (void*)&w2lg,
    (void*)&h1h, (void*)&h1l, (void*)&h2h, (void*)&h2l,
    (void*)&flags, (void*)&out
  };
  // Cooperative launch purely for the co-residency guarantee; sync is custom.
  (void)hipLaunchCooperativeKernel((void*)lstm_kernel, dim3(NBLK),
                                   dim3(NTHREADS), args, 0, stream);
}